// Round 1
// baseline (162.337 us; speedup 1.0000x reference)
//
#include <hip/hip_runtime.h>

#define BATCH 4096
#define DIM 64
#define KN 50
#define NL 3

// ---------------------------------------------------------------------------
// Kernel A: per-row fused gather + cumulative-mask neighbor sums + 3 MLP layers
// grid 1024 x 256 threads; each of the 4 waves owns one batch row.
// W staged once per block into LDS, padded stride 65 -> (lane+i)%32 banks,
// 2-way aliasing only (free on CDNA4).
// ---------------------------------------------------------------------------
__global__ __launch_bounds__(256) void rows_kernel(
    const int* __restrict__ user_ids,
    const int* __restrict__ item_ids,
    const int* __restrict__ nbrs,
    const float* __restrict__ mask,
    const float* __restrict__ user_table,
    const float* __restrict__ item_table,
    const float* __restrict__ Ws,
    const float* __restrict__ bs,
    float* __restrict__ Uout,
    float* __restrict__ Iout)
{
    __shared__ float Wlds[NL * 64 * 65];   // 48.75 KB, padded
    __shared__ float blds[NL * 64];
    __shared__ float xbuf[4][64];

    const int tid = threadIdx.x;

    // Stage Ws [3][64][64] into padded LDS (coalesced global reads).
    for (int idx = tid; idx < NL * 64 * 64; idx += 256) {
        const int l = idx >> 12;         // /4096
        const int rem = idx & 4095;
        const int j = rem >> 6;
        const int i = rem & 63;
        Wlds[l * (64 * 65) + j * 65 + i] = Ws[idx];
    }
    if (tid < NL * 64) blds[tid] = bs[tid];
    __syncthreads();

    const int wave = tid >> 6;
    const int lane = tid & 63;
    const int b = (blockIdx.x << 2) + wave;

    // Item embedding gather (row-major [B][64] into workspace).
    const int it = item_ids[b];
    Iout[b * DIM + lane] = item_table[it * DIM + lane];

    // User embedding.
    const int u = user_ids[b];
    float x = user_table[u * DIM + lane];

    // Lanes 0..49 cooperatively load this row's neighbor ids & weights.
    int ni = 0;
    float wi = 0.0f;
    if (lane < KN) {
        ni = nbrs[b * KN + lane];
        wi = mask[b * KN + lane];
    }

    // Cumulative mask: layer l uses mask^(l+1). Accumulate w, w^2, w^3 sums
    // in one gather pass. Shuffle-broadcast keeps the 50 gathers independent.
    float acc1 = 0.f, acc2 = 0.f, acc3 = 0.f;
    #pragma unroll
    for (int k = 0; k < KN; ++k) {
        const int nk = __shfl(ni, k);
        const float wk = __shfl(wi, k);
        const float v = user_table[nk * DIM + lane];
        const float w2 = wk * wk;
        acc1 = fmaf(wk, v, acc1);
        acc2 = fmaf(w2, v, acc2);
        acc3 = fmaf(w2 * wk, v, acc3);
    }
    const float inv = 1.0f / (float)KN;
    float nm0 = acc1 * inv, nm1 = acc2 * inv, nm2 = acc3 * inv;

    // 3 layers: y_j = relu(b[j] + sum_i (x_i + n_i) * W[j][i])
    #pragma unroll
    for (int l = 0; l < NL; ++l) {
        const float nm = (l == 0) ? nm0 : (l == 1) ? nm1 : nm2;
        const float t = x + nm;
        __syncthreads();                 // protect xbuf reuse across layers
        xbuf[wave][lane] = t;
        __syncthreads();
        float y = blds[l * 64 + lane];
        const float* wrow = &Wlds[l * (64 * 65) + lane * 65];
        #pragma unroll
        for (int i = 0; i < 64; ++i)
            y = fmaf(wrow[i], xbuf[wave][i], y);  // xbuf read = broadcast
        x = fmaxf(y, 0.0f);
    }
    Uout[b * DIM + lane] = x;
}

// ---------------------------------------------------------------------------
// Kernel B: scores = U [4096,64] @ V^T [64,4096], fp32 (no fp32 MFMA on CDNA4).
// 128x128 tile / block of 256 threads / 8x8 micro-tile.
// LDS holds both tiles k-major (transposed), 64 KB total -> 2 blocks/CU.
// ---------------------------------------------------------------------------
__global__ __launch_bounds__(256) void scores_kernel(
    const float* __restrict__ U,
    const float* __restrict__ V,
    float* __restrict__ C)
{
    __shared__ float Ut[64 * 128];   // [k][row]
    __shared__ float Vt[64 * 128];   // [k][col]

    const int tid = threadIdx.x;
    const int rowBase = blockIdx.y << 7;
    const int colBase = blockIdx.x << 7;

    // Stage: 128 rows x 16 float4 per matrix; coalesced loads, transposed store.
    const float4* U4 = (const float4*)(U + (size_t)rowBase * DIM);
    const float4* V4 = (const float4*)(V + (size_t)colBase * DIM);
    #pragma unroll
    for (int c = 0; c < 8; ++c) {
        const int flat = (c << 8) + tid;      // 0..2047 == row*16 + cv
        const int row = flat >> 4;
        const int cv = flat & 15;
        const float4 uv = U4[flat];
        const float4 vv = V4[flat];
        const int k0 = cv << 2;
        Ut[(k0 + 0) * 128 + row] = uv.x;
        Ut[(k0 + 1) * 128 + row] = uv.y;
        Ut[(k0 + 2) * 128 + row] = uv.z;
        Ut[(k0 + 3) * 128 + row] = uv.w;
        Vt[(k0 + 0) * 128 + row] = vv.x;
        Vt[(k0 + 1) * 128 + row] = vv.y;
        Vt[(k0 + 2) * 128 + row] = vv.z;
        Vt[(k0 + 3) * 128 + row] = vv.w;
    }
    __syncthreads();

    const int tx = tid & 15;
    const int ty = tid >> 4;

    float acc[8][8];
    #pragma unroll
    for (int i = 0; i < 8; ++i)
        #pragma unroll
        for (int j = 0; j < 8; ++j)
            acc[i][j] = 0.0f;

    #pragma unroll 4
    for (int k = 0; k < 64; ++k) {
        const float4 a0 = *(const float4*)&Ut[k * 128 + ty * 8];
        const float4 a1 = *(const float4*)&Ut[k * 128 + ty * 8 + 4];
        const float4 b0 = *(const float4*)&Vt[k * 128 + tx * 8];
        const float4 b1 = *(const float4*)&Vt[k * 128 + tx * 8 + 4];
        const float a[8] = {a0.x, a0.y, a0.z, a0.w, a1.x, a1.y, a1.z, a1.w};
        const float bb[8] = {b0.x, b0.y, b0.z, b0.w, b1.x, b1.y, b1.z, b1.w};
        #pragma unroll
        for (int i = 0; i < 8; ++i)
            #pragma unroll
            for (int j = 0; j < 8; ++j)
                acc[i][j] = fmaf(a[i], bb[j], acc[i][j]);
    }

    // Epilogue: coalesced float4 stores.
    #pragma unroll
    for (int i = 0; i < 8; ++i) {
        float* crow = C + (size_t)(rowBase + ty * 8 + i) * BATCH + colBase + tx * 8;
        *(float4*)(crow + 0) = make_float4(acc[i][0], acc[i][1], acc[i][2], acc[i][3]);
        *(float4*)(crow + 4) = make_float4(acc[i][4], acc[i][5], acc[i][6], acc[i][7]);
    }
}

extern "C" void kernel_launch(void* const* d_in, const int* in_sizes, int n_in,
                              void* d_out, int out_size, void* d_ws, size_t ws_size,
                              hipStream_t stream)
{
    const int* user_ids   = (const int*)d_in[0];
    const int* item_ids   = (const int*)d_in[1];
    const int* nbrs       = (const int*)d_in[2];
    const float* mask     = (const float*)d_in[3];
    const float* utable   = (const float*)d_in[4];
    const float* itable   = (const float*)d_in[5];
    const float* Ws       = (const float*)d_in[6];
    const float* bs       = (const float*)d_in[7];
    float* out = (float*)d_out;

    float* U = (float*)d_ws;               // [4096][64] final user embeddings
    float* I = U + BATCH * DIM;            // [4096][64] gathered item embeddings

    rows_kernel<<<BATCH / 4, 256, 0, stream>>>(user_ids, item_ids, nbrs, mask,
                                               utable, itable, Ws, bs, U, I);
    scores_kernel<<<dim3(32, 32), 256, 0, stream>>>(U, I, out);
}

// Round 2
// 141.674 us; speedup vs baseline: 1.1458x; 1.1458x over previous
//
#include <hip/hip_runtime.h>
#include <hip/hip_bf16.h>

#define BATCH 4096
#define DIM 64
#define KN 50
#define NL 3

typedef __attribute__((ext_vector_type(8))) short short8;   // 8 bf16 = 4 VGPRs
typedef __attribute__((ext_vector_type(4))) float f32x4;

// ---------------------------------------------------------------------------
// Kernel A: per-row fused gather + cumulative-mask neighbor sums + 3 MLP
// layers, emitting bf16 user/item embeddings for the MFMA scores GEMM.
// 1024 blocks x 256 threads; each of the 4 waves owns one batch row.
// W staged in LDS at stride 65 -> (lane+i)%32 banks, 2-way aliasing = free.
// xbuf is wave-private: no __syncthreads needed (lockstep wave, in-order LDS).
// ---------------------------------------------------------------------------
__global__ __launch_bounds__(256) void rows_kernel(
    const int* __restrict__ user_ids,
    const int* __restrict__ item_ids,
    const int* __restrict__ nbrs,
    const float* __restrict__ mask,
    const float* __restrict__ user_table,
    const float* __restrict__ item_table,
    const float* __restrict__ Ws,
    const float* __restrict__ bs,
    __hip_bfloat16* __restrict__ Uout,
    __hip_bfloat16* __restrict__ Iout)
{
    __shared__ float Wlds[NL * 64 * 65];   // 48.75 KB, padded
    __shared__ float blds[NL * 64];
    __shared__ float xbuf[4][64];

    const int tid = threadIdx.x;

    // Stage Ws [3][64][64] into padded LDS (coalesced global reads).
    for (int idx = tid; idx < NL * 64 * 64; idx += 256) {
        const int l = idx >> 12;
        const int rem = idx & 4095;
        const int j = rem >> 6;
        const int i = rem & 63;
        Wlds[l * (64 * 65) + j * 65 + i] = Ws[idx];
    }
    if (tid < NL * 64) blds[tid] = bs[tid];
    __syncthreads();

    const int wave = tid >> 6;
    const int lane = tid & 63;
    const int b = (blockIdx.x << 2) + wave;

    // Item embedding gather -> bf16.
    const int it = item_ids[b];
    Iout[b * DIM + lane] = __float2bfloat16(item_table[it * DIM + lane]);

    // User embedding.
    const int u = user_ids[b];
    float x = user_table[u * DIM + lane];

    // Lanes 0..49 hold this row's neighbor ids & weights.
    int ni = 0;
    float wi = 0.0f;
    if (lane < KN) {
        ni = nbrs[b * KN + lane];
        wi = mask[b * KN + lane];
    }

    // Layer l uses mask^(l+1): accumulate w, w^2, w^3 sums in one pass.
    float acc1 = 0.f, acc2 = 0.f, acc3 = 0.f;
    #pragma unroll
    for (int k = 0; k < KN; ++k) {
        const int nk = __shfl(ni, k);
        const float wk = __shfl(wi, k);
        const float v = user_table[nk * DIM + lane];
        const float w2 = wk * wk;
        acc1 = fmaf(wk, v, acc1);
        acc2 = fmaf(w2, v, acc2);
        acc3 = fmaf(w2 * wk, v, acc3);
    }
    const float inv = 1.0f / (float)KN;
    const float nm0 = acc1 * inv, nm1 = acc2 * inv, nm2 = acc3 * inv;

    // 3 layers: y_j = relu(b[j] + sum_i (x_i + n_i) * W[j][i])
    #pragma unroll
    for (int l = 0; l < NL; ++l) {
        const float nm = (l == 0) ? nm0 : (l == 1) ? nm1 : nm2;
        xbuf[wave][lane] = x + nm;        // wave-private; lgkmcnt ordering only
        float y = blds[l * 64 + lane];
        const float* wrow = &Wlds[l * (64 * 65) + lane * 65];
        #pragma unroll
        for (int i = 0; i < 64; ++i)
            y = fmaf(wrow[i], xbuf[wave][i], y);   // xbuf read = broadcast
        x = fmaxf(y, 0.0f);
    }
    Uout[b * DIM + lane] = __float2bfloat16(x);
}

// ---------------------------------------------------------------------------
// Kernel B: scores = U [4096,64] @ I^T via mfma_f32_16x16x32_bf16, zero LDS.
// Fragment layout (m89-verified): lane holds row/col (lane&15), 8 contiguous
// k at (lane>>4)*8 -> one 16B coalesced global load per fragment; U,I are
// 512 KB each -> L2-resident. C/D: col=lane&15, row=(lane>>4)*4+reg.
// Block = 4 waves; wave w owns rows [blockIdx.y*64 + w*16, +16), iterates 16
// col-tiles of 16 in colgroup blockIdx.x*256. Grid 16x64 = 1024 blocks.
// Bound by the 64 MiB C write.
// ---------------------------------------------------------------------------
__global__ __launch_bounds__(256) void scores_kernel(
    const __hip_bfloat16* __restrict__ U,
    const __hip_bfloat16* __restrict__ V,
    float* __restrict__ C)
{
    const int tid = threadIdx.x;
    const int wave = tid >> 6;
    const int lane = tid & 63;
    const int quad = lane >> 4;
    const int l16 = lane & 15;

    const int row0 = (blockIdx.y << 6) + (wave << 4);
    const int colG = blockIdx.x << 8;

    const short* Us = (const short*)U;
    const short* Vs = (const short*)V;

    // A fragments for this wave's 16 rows (K=64 -> two k-halves), kept in regs.
    const short* ap = Us + (row0 + l16) * DIM + quad * 8;
    const short8 a0 = *(const short8*)(ap);
    const short8 a1 = *(const short8*)(ap + 32);

    #pragma unroll 4
    for (int ct = 0; ct < 16; ++ct) {
        const int col0 = colG + (ct << 4);
        const short* bp = Vs + (col0 + l16) * DIM + quad * 8;
        const short8 b0 = *(const short8*)(bp);
        const short8 b1 = *(const short8*)(bp + 32);
        f32x4 acc = {0.f, 0.f, 0.f, 0.f};
        acc = __builtin_amdgcn_mfma_f32_16x16x32_bf16(a0, b0, acc, 0, 0, 0);
        acc = __builtin_amdgcn_mfma_f32_16x16x32_bf16(a1, b1, acc, 0, 0, 0);
        float* cp = C + (size_t)(row0 + (quad << 2)) * BATCH + col0 + l16;
        #pragma unroll
        for (int r = 0; r < 4; ++r)
            cp[(size_t)r * BATCH] = acc[r];
    }
}

extern "C" void kernel_launch(void* const* d_in, const int* in_sizes, int n_in,
                              void* d_out, int out_size, void* d_ws, size_t ws_size,
                              hipStream_t stream)
{
    const int* user_ids   = (const int*)d_in[0];
    const int* item_ids   = (const int*)d_in[1];
    const int* nbrs       = (const int*)d_in[2];
    const float* mask     = (const float*)d_in[3];
    const float* utable   = (const float*)d_in[4];
    const float* itable   = (const float*)d_in[5];
    const float* Ws       = (const float*)d_in[6];
    const float* bs       = (const float*)d_in[7];
    float* out = (float*)d_out;

    __hip_bfloat16* Ubf = (__hip_bfloat16*)d_ws;        // [4096][64] bf16
    __hip_bfloat16* Ibf = Ubf + BATCH * DIM;            // [4096][64] bf16

    rows_kernel<<<BATCH / 4, 256, 0, stream>>>(user_ids, item_ids, nbrs, mask,
                                               utable, itable, Ws, bs, Ubf, Ibf);
    scores_kernel<<<dim3(16, 64), 256, 0, stream>>>(Ubf, Ibf, out);
}